// Round 2
// baseline (901.170 us; speedup 1.0000x reference)
//
#include <hip/hip_runtime.h>
#include <hip/hip_bf16.h>

typedef unsigned short u16;
typedef unsigned long long u64;
typedef __attribute__((ext_vector_type(4))) short short4v;
typedef __attribute__((ext_vector_type(8))) short short8;
typedef __attribute__((ext_vector_type(4))) float floatx4;

__device__ __forceinline__ u16 f2bf(float f) {
    union { float f; unsigned u; } v; v.f = f;
    unsigned r = v.u + 0x7FFF + ((v.u >> 16) & 1);
    return (u16)(r >> 16);
}

// ---------------------------------------------------------------------------
// Wstack fragment builder (validated rounds 1-9).
// element (k,n) at: (k>>5)*16384 + (n>>4)*512 + ((k>>3)&3)*128 + (n&15)*8 + (k&7)
__global__ void k_wstack2(const float* __restrict__ basis, const float* __restrict__ comb,
                          const float* __restrict__ selfW, u16* __restrict__ wf) {
    int bi = blockIdx.x, t = threadIdx.x;
    int kr = t >> 7;             // 0..1
    int nb = (t & 127) * 4;      // n base
    for (int it = 0; it < 4; ++it) {
        int k = bi * 8 + it * 2 + kr;
        float v0, v1, v2, v3;
        if (k < 6144) {
            int r = k >> 9, h = k & 511;
            v0 = v1 = v2 = v3 = 0.f;
            for (int q = 0; q < 6; ++q) {
                float c = comb[r * 6 + q];
                const float4 bz = *(const float4*)(basis + ((size_t)(q * 512 + h)) * 512 + nb);
                v0 += c * bz.x; v1 += c * bz.y; v2 += c * bz.z; v3 += c * bz.w;
            }
        } else {
            int kk = k - 6144;
            v0 = selfW[(size_t)(nb + 0) * 512 + kk];
            v1 = selfW[(size_t)(nb + 1) * 512 + kk];
            v2 = selfW[(size_t)(nb + 2) * 512 + kk];
            v3 = selfW[(size_t)(nb + 3) * 512 + kk];
        }
        float vv[4] = {v0, v1, v2, v3};
        for (int i = 0; i < 4; ++i) {
            int n = nb + i;
            wf[(size_t)(k >> 5) * 16384 + (n >> 4) * 512 + ((k >> 3) & 3) * 128 + (n & 15) * 8 + (k & 7)] = f2bf(vv[i]);
        }
    }
}

// ---------------------------------------------------------------------------
// Adjacency -> pre-expanded bf16 MFMA fragments.
// variant 0: plain mask (pass-1 graph)  variant 1: remapped+parity (pass-2 graph)
// Layout: abf[(b*12+r)*4096 + f*512 + lane*8 + j]   (f = i*2+par)
// value = bit(row = (f>>1)*16 + (lane&15), m = (f&1)*32 + (lane>>4)*8 + j).
__global__ void k_adjexp(const int* __restrict__ A, u16* __restrict__ abf, int variant) {
    int bi = blockIdx.x;          // b*12 + r
    int b = bi / 12, r = bi % 12;
    const int* Ab = A + (size_t)(b * 13 + (r + 1)) * 62 * 62;
    __shared__ int tile[62 * 62];
    __shared__ u64 sm[64];
    for (int i = threadIdx.x; i < 3844; i += 256) tile[i] = Ab[i];
    __syncthreads();
    int n = threadIdx.x;
    if (n < 64) {
        u64 m = 0;
        if (variant == 0) {
            if (n < 62)
                for (int mm = 0; mm < 62; ++mm)
                    if (tile[n * 62 + mm]) m |= 1ull << mm;
        } else {
            if (n < 63) {
                int oi = (n == 62) ? 63 : n;
                for (int mm = 0; mm < 63; ++mm) {
                    int oj = (mm == 62) ? 63 : mm;
                    int val = (oi < 62 && oj < 62) ? (tile[oi * 62 + oj] ? 1 : 0) : 0;
                    int lo = (oi < oj) ? oi : oj, hi = (oi < oj) ? oj : oi;
                    if (hi == lo + 2) {
                        int p = (lo >> 1) & 1;
                        int chp = ((lo & 1) == 0) ? (p ? 12 : 11) : (p ? 11 : 12);
                        if (r + 1 == chp) val = 1;
                    }
                    if (val) m |= 1ull << mm;
                }
            }
        }
        sm[n] = m;
    }
    __syncthreads();
    // expand to bf16 fragments; coalesced: consecutive t -> consecutive addrs
    int t = threadIdx.x;
    int f = t >> 5;               // 0..7
    int lane0 = (t & 31) * 2;     // 0,2,...,62
    size_t base = (size_t)bi * 4096;
    #pragma unroll
    for (int dl = 0; dl < 2; ++dl) {
        int lane = lane0 + dl;
        int row = ((f >> 1) << 4) + (lane & 15);
        int mbase = (f & 1) * 32 + (lane >> 4) * 8;
        u64 msk = sm[row];
        size_t addr = base + (size_t)f * 512 + (size_t)lane * 8;
        #pragma unroll
        for (int j = 0; j < 8; ++j)
            abf[addr + j] = (u16)(((msk >> (mbase + j)) & 1) ? 0x3F80 : 0);
    }
}

// ---------------------------------------------------------------------------
// initial embedding -> mi1 rows 60..63 ; mi2 rows 62,63
__global__ void k_prep(const int* __restrict__ player,
                       const float* __restrict__ pAx, const float* __restrict__ pAy,
                       const float* __restrict__ pBx, const float* __restrict__ pBy,
                       const float* __restrict__ emb, const float* __restrict__ cW,
                       const float* __restrict__ cb, const float* __restrict__ inW,
                       const float* __restrict__ inb,
                       u16* __restrict__ mi1, u16* __restrict__ mi2) {
    int b = blockIdx.x, t = threadIdx.x;
    __shared__ float feat[2][64];
    if (t < 64) {
        int j = t >> 5, d = t & 31;
        float X = j ? pBx[b] : pAx[b];
        float Y = j ? pBy[b] : pAy[b];
        feat[j][d] = fmaxf(cW[d * 2] * X + cW[d * 2 + 1] * Y + cb[d], 0.f);
        feat[j][32 + d] = emb[player[b * 2 + j] * 32 + d];
    }
    __syncthreads();
    for (int h = t; h < 512; h += 256) {
        float a0 = inb[h], a1 = inb[h];
        const float* wrow = inW + h * 64;
        #pragma unroll
        for (int d = 0; d < 64; ++d) {
            float wv = wrow[d];
            a0 += wv * feat[0][d];
            a1 += wv * feat[1][d];
        }
        u16 v0 = f2bf(a0), v1 = f2bf(a1);
        size_t base = (size_t)b * 64 * 512;
        mi1[base + 60 * 512 + h] = v0;
        mi1[base + 61 * 512 + h] = v1;
        mi1[base + 62 * 512 + h] = 0;
        mi1[base + 63 * 512 + h] = 0;
        mi2[base + 62 * 512 + h] = v1;
        mi2[base + 63 * 512 + h] = 0;
    }
}

// enc f32 -> mi1 rows 0..59 ; mi2 rows 0..57
__global__ void k_cast(const float* __restrict__ enc, u16* __restrict__ mi1, u16* __restrict__ mi2) {
    long long e = ((long long)blockIdx.x * 256 + threadIdx.x) * 8;
    if (e >= 256LL * 60 * 512) return;
    int b = (int)(e / (60 * 512));
    int rm = (int)(e % (60 * 512));
    int n = rm / 512, h = rm % 512;
    for (int i = 0; i < 8; ++i) {
        u16 v = f2bf(enc[e + i]);
        mi1[((size_t)b * 64 + n) * 512 + h + i] = v;
        if (n < 58) mi2[((size_t)b * 64 + n) * 512 + h + i] = v;
    }
}

// ---------------------------------------------------------------------------
// Fused RGCN layer. v9 = proven v7 structure (f2bf packing) + adjacency
// fragments loaded pre-expanded from global (no per-r bitmask->bf16 VALU).
// Block = (1 batch, 64-col tile ct), 256 thr = 4 waves; wave w = K-quarter.
__global__ __launch_bounds__(256, 2)
void k_fused(const u16* __restrict__ x, const u16* __restrict__ adjbf,
             const u16* __restrict__ wf, int mode,
             u16* __restrict__ o16, float* __restrict__ o32) {
    int ct = blockIdx.x & 7, b = blockIdx.x >> 3;
    int t = threadIdx.x, lane = t & 63, w = t >> 6;
    int l15 = lane & 15, lq = lane >> 4;

    __shared__ __align__(16) u16 zs[64 * 264];   // [col][m' 0..255]

    // x fragments: all 64 rows, K-quarter w (one-time load)
    short8 xf[16];
    {
        const u16* xw = x + (size_t)b * 64 * 512 + w * 128 + lq * 8;
        #pragma unroll
        for (int mt = 0; mt < 4; ++mt)
            #pragma unroll
            for (int ks = 0; ks < 4; ++ks)
                xf[mt * 4 + ks] = *(const short8*)(xw + (mt * 16 + l15) * 512 + ks * 32);
    }

    const u16* wbase = wf + (size_t)(ct * 4) * 512 + (size_t)lane * 8;
    const u16* abase = adjbf + (size_t)b * 12 * 4096 + (size_t)lane * 8;

    floatx4 ay[4];
    #pragma unroll
    for (int i = 0; i < 4; ++i) ay[i] = (floatx4)(0.f);

    // prefetch r=0, ks=0/1 W fragments
    short8 wp[8];
    {
        const u16* wr0 = wbase + (size_t)(w * 4) * 16384;
        #pragma unroll
        for (int i = 0; i < 4; ++i) {
            wp[i]     = *(const short8*)(wr0 + (size_t)i * 512);
            wp[4 + i] = *(const short8*)(wr0 + 16384 + (size_t)i * 512);
        }
    }

    for (int r = 0; r < 13; ++r) {
        // adj fragments: loads issued here so latency hides under Z-phase MFMAs
        short8 adjf[8];
        if (mode == 0) {
            if (r < 12) {
                const u16* ab = abase + (size_t)r * 4096;
                #pragma unroll
                for (int f = 0; f < 8; ++f) adjf[f] = *(const short8*)(ab + f * 512);
            } else {
                // identity relation, in-register
                #pragma unroll
                for (int i2 = 0; i2 < 4; ++i2)
                    #pragma unroll
                    for (int par = 0; par < 2; ++par)
                        #pragma unroll
                        for (int j = 0; j < 8; ++j)
                            adjf[i2 * 2 + par][j] =
                                (short)((i2 * 16 + l15 == par * 32 + lq * 8 + j) ? 0x3F80 : 0);
            }
        } else {
            if (r < 12) {
                const u16* ab = abase + (size_t)r * 4096;
                adjf[6] = *(const short8*)(ab + 6 * 512);
                adjf[7] = *(const short8*)(ab + 7 * 512);
            } else {
                #pragma unroll
                for (int par = 0; par < 2; ++par)
                    #pragma unroll
                    for (int j = 0; j < 8; ++j)
                        adjf[6 + par][j] =
                            (short)((48 + l15 == par * 32 + lq * 8 + j) ? 0x3F80 : 0);
            }
        }

        // ---- Z-phase: az = x_q @ W[r, quarter w]
        const u16* wr = wbase + (size_t)(r * 16 + w * 4) * 16384;
        floatx4 az[16];
        #pragma unroll
        for (int i = 0; i < 16; ++i) az[i] = (floatx4)(0.f);
        short8 wv[4], wn_[4];
        // issue ks=2 loads, then MFMA ks=0 from prefetched wp
        #pragma unroll
        for (int i = 0; i < 4; ++i) wv[i] = *(const short8*)(wr + 2 * 16384 + (size_t)i * 512);
        #pragma unroll
        for (int mt = 0; mt < 4; ++mt)
            #pragma unroll
            for (int i = 0; i < 4; ++i)
                az[mt * 4 + i] = __builtin_amdgcn_mfma_f32_16x16x32_bf16(xf[mt * 4 + 0], wp[i], az[mt * 4 + i], 0, 0, 0);
        // issue ks=3 loads, then MFMA ks=1 from prefetched wp
        #pragma unroll
        for (int i = 0; i < 4; ++i) wn_[i] = *(const short8*)(wr + 3 * 16384 + (size_t)i * 512);
        #pragma unroll
        for (int mt = 0; mt < 4; ++mt)
            #pragma unroll
            for (int i = 0; i < 4; ++i)
                az[mt * 4 + i] = __builtin_amdgcn_mfma_f32_16x16x32_bf16(xf[mt * 4 + 1], wp[4 + i], az[mt * 4 + i], 0, 0, 0);
        // ks=2, ks=3
        #pragma unroll
        for (int mt = 0; mt < 4; ++mt)
            #pragma unroll
            for (int i = 0; i < 4; ++i)
                az[mt * 4 + i] = __builtin_amdgcn_mfma_f32_16x16x32_bf16(xf[mt * 4 + 2], wv[i], az[mt * 4 + i], 0, 0, 0);
        #pragma unroll
        for (int mt = 0; mt < 4; ++mt)
            #pragma unroll
            for (int i = 0; i < 4; ++i)
                az[mt * 4 + i] = __builtin_amdgcn_mfma_f32_16x16x32_bf16(xf[mt * 4 + 3], wn_[i], az[mt * 4 + i], 0, 0, 0);

        __syncthreads();   // prior agg's zs reads complete

        // ---- write Z-partials: zs[col][w*64 + row]
        #pragma unroll
        for (int mt = 0; mt < 4; ++mt)
            #pragma unroll
            for (int i = 0; i < 4; ++i) {
                short4v pk;
                #pragma unroll
                for (int rr = 0; rr < 4; ++rr) pk[rr] = (short)f2bf(az[mt * 4 + i][rr]);
                *(short4v*)&zs[(i * 16 + l15) * 264 + w * 64 + mt * 16 + lq * 4] = pk;
            }

        // ---- prefetch r+1 ks=0/1 W frags: in flight across the agg phase
        if (r < 12) {
            const u16* wrn = wbase + (size_t)((r + 1) * 16 + w * 4) * 16384;
            #pragma unroll
            for (int i = 0; i < 4; ++i) {
                wp[i]     = *(const short8*)(wrn + (size_t)i * 512);
                wp[4 + i] = *(const short8*)(wrn + 16384 + (size_t)i * 512);
            }
        }

        __syncthreads();   // zs visible

        // ---- agg: ay^T += Z^T @ adj^T  (A = zs own col-band, B = adj frags)
        if (mode == 0) {
            #pragma unroll
            for (int k2 = 0; k2 < 8; ++k2) {
                short8 af = *(const short8*)&zs[(w * 16 + l15) * 264 + k2 * 32 + lq * 8];
                #pragma unroll
                for (int i = 0; i < 4; ++i)
                    ay[i] = __builtin_amdgcn_mfma_f32_16x16x32_bf16(af, adjf[i * 2 + (k2 & 1)], ay[i], 0, 0, 0);
            }
        } else {
            #pragma unroll
            for (int k2 = 0; k2 < 8; ++k2) {
                short8 af = *(const short8*)&zs[(w * 16 + l15) * 264 + k2 * 32 + lq * 8];
                ay[3] = __builtin_amdgcn_mfma_f32_16x16x32_bf16(af, adjf[6 + (k2 & 1)], ay[3], 0, 0, 0);
            }
        }
    }

    // ---- epilogue: lane holds y[row = i*16+l15][col = ct*64 + w*16 + lq*4 + rr]
    int colb = ct * 64 + w * 16 + lq * 4;
    #pragma unroll
    for (int i = 0; i < 4; ++i) {
        int row = i * 16 + l15;
        if (mode == 0) {
            short4v pk;
            #pragma unroll
            for (int rr = 0; rr < 4; ++rr) pk[rr] = (short)f2bf(fmaxf(ay[i][rr], 0.f));
            *(short4v*)(o16 + ((size_t)b * 64 + row) * 512 + colb) = pk;
        } else if (mode == 1) {
            if (i == 3 && row >= 58 && row <= 61) {
                short4v pk;
                #pragma unroll
                for (int rr = 0; rr < 4; ++rr)
                    pk[rr] = (short)f2bf(1.f / (1.f + __expf(-ay[3][rr])));
                *(short4v*)(o16 + ((size_t)b * 64 + row) * 512 + colb) = pk;
            }
        } else {
            if (i == 3 && (row == 60 || row == 62)) {
                float4 pv;
                pv.x = 1.f / (1.f + __expf(-ay[3][0]));
                pv.y = 1.f / (1.f + __expf(-ay[3][1]));
                pv.z = 1.f / (1.f + __expf(-ay[3][2]));
                pv.w = 1.f / (1.f + __expf(-ay[3][3]));
                int slot = (row == 60) ? (b * 2) : (b * 2 + 1);
                *(float4*)(o32 + (size_t)slot * 512 + colb) = pv;
            }
        }
    }
}

// logits = [black|white] @ type_W^T + type_b
__global__ void k_final(const float* __restrict__ t2, const float* __restrict__ tW,
                        const float* __restrict__ tb, float* __restrict__ outp) {
    int b = blockIdx.x, l = threadIdx.x;   // 64 threads
    float a[11];
    #pragma unroll
    for (int j = 0; j < 11; ++j) a[j] = 0.f;
    for (int it = 0; it < 16; ++it) {
        int h = it * 64 + l;
        float c = (h < 512) ? t2[(b * 2 + 1) * 512 + h] : t2[(b * 2 + 0) * 512 + (h - 512)];
        #pragma unroll
        for (int j = 0; j < 11; ++j) a[j] += c * tW[j * 1024 + h];
    }
    #pragma unroll
    for (int j = 0; j < 11; ++j) {
        float v = a[j];
        for (int off = 32; off > 0; off >>= 1) v += __shfl_down(v, off, 64);
        if (l == 0) outp[b * 11 + j] = v + tb[j];
    }
}

// ---------------------------------------------------------------------------
extern "C" void kernel_launch(void* const* d_in, const int* in_sizes, int n_in,
                              void* d_out, int out_size, void* d_ws, size_t ws_size,
                              hipStream_t stream) {
    const int*   player = (const int*)d_in[0];
    const float* enc    = (const float*)d_in[2];
    const int*   adjm   = (const int*)d_in[3];
    const float* pAx    = (const float*)d_in[4];
    const float* pAy    = (const float*)d_in[5];
    const float* pBx    = (const float*)d_in[6];
    const float* pBy    = (const float*)d_in[7];
    const float* emb    = (const float*)d_in[8];
    const float* cW     = (const float*)d_in[9];
    const float* cb     = (const float*)d_in[10];
    const float* inW    = (const float*)d_in[11];
    const float* inb    = (const float*)d_in[12];
    const float* basis0 = (const float*)d_in[13];
    const float* comb0  = (const float*)d_in[14];
    const float* self0  = (const float*)d_in[15];
    const float* basis1 = (const float*)d_in[16];
    const float* comb1  = (const float*)d_in[17];
    const float* self1  = (const float*)d_in[18];
    const float* typeW  = (const float*)d_in[19];
    const float* typeb  = (const float*)d_in[20];

    char* ws = (char*)d_ws;
    size_t off = 0;
    auto alloc = [&](size_t bytes) -> void* {
        void* p = ws + off;
        off = (off + bytes + 255) & ~(size_t)255;
        return p;
    };
    // Time-aliased workspace (peak 89.1 MB):
    //   mi1 region: mi1 (prep..pass1) -> x12b (pass3..pass4)
    //   x12 region: x12 (pass1..pass2) -> t2 (pass4..final)
    //   abf region: abfA (adjexp0..pass2) -> abfB (adjexp1..pass4)
    u16* mi1   = (u16*)alloc(256UL * 64 * 512 * 2);
    u16* mi2   = (u16*)alloc(256UL * 64 * 512 * 2);
    u16* x12   = (u16*)alloc(256UL * 64 * 512 * 2);
    u16* abf   = (u16*)alloc(256UL * 12 * 4096 * 2);
    u16* wf0   = (u16*)alloc(208UL * 32 * 64 * 8 * 2);
    u16* wf1   = (u16*)alloc(208UL * 32 * 64 * 8 * 2);
    u16* x12b  = mi1;             // mi1 dead after pass 1
    float* t2  = (float*)x12;     // x12 dead after pass 2

    k_wstack2<<<832, 256, 0, stream>>>(basis0, comb0, self0, wf0);
    k_wstack2<<<832, 256, 0, stream>>>(basis1, comb1, self1, wf1);
    k_adjexp<<<3072, 256, 0, stream>>>(adjm, abf, 0);
    k_prep<<<256, 256, 0, stream>>>(player, pAx, pAy, pBx, pBy, emb, cW, cb, inW, inb, mi1, mi2);
    k_cast<<<3840, 256, 0, stream>>>(enc, mi1, mi2);

    // rgcn pass 1
    k_fused<<<2048, 256, 0, stream>>>(mi1, abf, wf0, 0, x12, nullptr);
    k_fused<<<2048, 256, 0, stream>>>(x12, abf, wf1, 1, mi2, nullptr);
    // regenerate adjacency fragments for the pruned pass-2 graph
    k_adjexp<<<3072, 256, 0, stream>>>(adjm, abf, 1);
    // rgcn pass 2
    k_fused<<<2048, 256, 0, stream>>>(mi2, abf, wf0, 0, x12b, nullptr);
    k_fused<<<2048, 256, 0, stream>>>(x12b, abf, wf1, 2, nullptr, t2);

    k_final<<<256, 64, 0, stream>>>(t2, typeW, typeb, (float*)d_out);
}

// Round 3
// 705.986 us; speedup vs baseline: 1.2765x; 1.2765x over previous
//
#include <hip/hip_runtime.h>
#include <hip/hip_bf16.h>

typedef unsigned short u16;
typedef unsigned long long u64;
typedef __attribute__((ext_vector_type(4))) short short4v;
typedef __attribute__((ext_vector_type(8))) short short8;
typedef __attribute__((ext_vector_type(4))) float floatx4;

__device__ __forceinline__ u16 f2bf(float f) {
    union { float f; unsigned u; } v; v.f = f;
    unsigned r = v.u + 0x7FFF + ((v.u >> 16) & 1);
    return (u16)(r >> 16);
}

// ---------------------------------------------------------------------------
// Wcat stack: 7 slabs [B_0..B_5, selfW^T], K = 3584, fragment layout validated
// (same as k_wstack2): element (k,n) at
//   (k>>5)*16384 + (n>>4)*512 + ((k>>3)&3)*128 + (n&15)*8 + (k&7)
// value = k<3072 ? basis[k>>9][k&511][n] : selfW[n][k-3072]
__global__ void k_wcat(const float* __restrict__ basis, const float* __restrict__ selfW,
                       u16* __restrict__ wf) {
    int bi = blockIdx.x, t = threadIdx.x;
    int kr = t >> 7;             // 0..1
    int nb = (t & 127) * 4;      // n base
    for (int it = 0; it < 4; ++it) {
        int k = bi * 8 + it * 2 + kr;     // 0..3583 over grid 448
        float v0, v1, v2, v3;
        if (k < 3072) {
            int q = k >> 9, h = k & 511;
            const float4 bz = *(const float4*)(basis + ((size_t)(q * 512 + h)) * 512 + nb);
            v0 = bz.x; v1 = bz.y; v2 = bz.z; v3 = bz.w;
        } else {
            int kk = k - 3072;
            v0 = selfW[(size_t)(nb + 0) * 512 + kk];
            v1 = selfW[(size_t)(nb + 1) * 512 + kk];
            v2 = selfW[(size_t)(nb + 2) * 512 + kk];
            v3 = selfW[(size_t)(nb + 3) * 512 + kk];
        }
        float vv[4] = {v0, v1, v2, v3};
        for (int i = 0; i < 4; ++i) {
            int n = nb + i;
            wf[(size_t)(k >> 5) * 16384 + (n >> 4) * 512 + ((k >> 3) & 3) * 128 + (n & 15) * 8 + (k & 7)] = f2bf(vv[i]);
        }
    }
}

// ---------------------------------------------------------------------------
// Weighted adjacency fragments: A_q = sum_r comb[r][q] * adj_r, expanded to bf16
// MFMA fragments (layout identical to validated abf; serves as A- or B-operand):
//   aq[set][(b*6+q)*4096 + f*512 + lane*8 + j]
//   value = A_q[row = (f>>1)*16 + (lane&15), col = (f&1)*32 + (lane>>4)*8 + j]
// set 0 = comb0-weighted, set 1 = comb1-weighted.
// variant 0: raw 62x62 masks (pass 1); variant 1: remapped + parity (pass 2).
#define AQ_SETSTRIDE (256UL * 6 * 4096)
__global__ void k_adjq(const int* __restrict__ A, const float* __restrict__ comb0,
                       const float* __restrict__ comb1, u16* __restrict__ aq, int variant) {
    int b = blockIdx.x, t = threadIdx.x;
    __shared__ u64 sm[12][64];
    __shared__ float cmb[2][12][6];
    if (t < 72) { cmb[0][t / 6][t % 6] = comb0[t]; cmb[1][t / 6][t % 6] = comb1[t]; }
    // masks: thread (r = rr*4 + t>>6, n = t&63)
    for (int rr = 0; rr < 3; ++rr) {
        int r = rr * 4 + (t >> 6), n = t & 63;
        const int* Ab = A + (size_t)(b * 13 + (r + 1)) * 62 * 62;
        u64 m = 0;
        if (variant == 0) {
            if (n < 62)
                for (int mm = 0; mm < 62; ++mm)
                    if (Ab[n * 62 + mm]) m |= 1ull << mm;
        } else {
            if (n < 63) {
                int oi = (n == 62) ? 63 : n;
                for (int mm = 0; mm < 63; ++mm) {
                    int oj = (mm == 62) ? 63 : mm;
                    int val = (oi < 62 && oj < 62) ? (Ab[oi * 62 + oj] ? 1 : 0) : 0;
                    int lo = (oi < oj) ? oi : oj, hi = (oi < oj) ? oj : oi;
                    if (hi == lo + 2) {
                        int p = (lo >> 1) & 1;
                        int chp = ((lo & 1) == 0) ? (p ? 12 : 11) : (p ? 11 : 12);
                        if (r + 1 == chp) val = 1;
                    }
                    if (val) m |= 1ull << mm;
                }
            }
        }
        sm[r][n] = m;
    }
    __syncthreads();
    // expansion: 4096 positions x 2 sets x 6 q; pos = ii*256 + t (coalesced stores)
    for (int ii = 0; ii < 16; ++ii) {
        int pos = ii * 256 + t;
        int f = pos >> 9, lane = (pos >> 3) & 63, j = pos & 7;
        int row = ((f >> 1) << 4) + (lane & 15);
        int mb  = ((f & 1) << 5) + ((lane >> 4) << 3) + j;
        float bits[12];
        #pragma unroll
        for (int r = 0; r < 12; ++r) bits[r] = (float)((sm[r][row] >> mb) & 1ull);
        #pragma unroll
        for (int s = 0; s < 2; ++s)
            #pragma unroll
            for (int q = 0; q < 6; ++q) {
                float v = 0.f;
                #pragma unroll
                for (int r = 0; r < 12; ++r) v += bits[r] * cmb[s][r][q];
                aq[(size_t)s * AQ_SETSTRIDE + ((size_t)b * 6 + q) * 4096 + pos] = f2bf(v);
            }
    }
}

// ---------------------------------------------------------------------------
// initial embedding -> mi1 rows 60..63 ; mi2 rows 62,63  (unchanged, validated)
__global__ void k_prep(const int* __restrict__ player,
                       const float* __restrict__ pAx, const float* __restrict__ pAy,
                       const float* __restrict__ pBx, const float* __restrict__ pBy,
                       const float* __restrict__ emb, const float* __restrict__ cW,
                       const float* __restrict__ cb, const float* __restrict__ inW,
                       const float* __restrict__ inb,
                       u16* __restrict__ mi1, u16* __restrict__ mi2) {
    int b = blockIdx.x, t = threadIdx.x;
    __shared__ float feat[2][64];
    if (t < 64) {
        int j = t >> 5, d = t & 31;
        float X = j ? pBx[b] : pAx[b];
        float Y = j ? pBy[b] : pAy[b];
        feat[j][d] = fmaxf(cW[d * 2] * X + cW[d * 2 + 1] * Y + cb[d], 0.f);
        feat[j][32 + d] = emb[player[b * 2 + j] * 32 + d];
    }
    __syncthreads();
    for (int h = t; h < 512; h += 256) {
        float a0 = inb[h], a1 = inb[h];
        const float* wrow = inW + h * 64;
        #pragma unroll
        for (int d = 0; d < 64; ++d) {
            float wv = wrow[d];
            a0 += wv * feat[0][d];
            a1 += wv * feat[1][d];
        }
        u16 v0 = f2bf(a0), v1 = f2bf(a1);
        size_t base = (size_t)b * 64 * 512;
        mi1[base + 60 * 512 + h] = v0;
        mi1[base + 61 * 512 + h] = v1;
        mi1[base + 62 * 512 + h] = 0;
        mi1[base + 63 * 512 + h] = 0;
        mi2[base + 62 * 512 + h] = v1;
        mi2[base + 63 * 512 + h] = 0;
    }
}

// enc f32 -> mi1 rows 0..59 ; mi2 rows 0..57  (unchanged, validated)
__global__ void k_cast(const float* __restrict__ enc, u16* __restrict__ mi1, u16* __restrict__ mi2) {
    long long e = ((long long)blockIdx.x * 256 + threadIdx.x) * 8;
    if (e >= 256LL * 60 * 512) return;
    int b = (int)(e / (60 * 512));
    int rm = (int)(e % (60 * 512));
    int n = rm / 512, h = rm % 512;
    for (int i = 0; i < 8; ++i) {
        u16 v = f2bf(enc[e + i]);
        mi1[((size_t)b * 64 + n) * 512 + h + i] = v;
        if (n < 58) mi2[((size_t)b * 64 + n) * 512 + h + i] = v;
    }
}

// ---------------------------------------------------------------------------
// Full RGCN layer via basis decomposition:
//   Y = relu( sum_q (A_q @ X) @ B_q  +  X @ selfW^T )
// Block = 1 batch, 512 thr = 8 waves; wave w owns output col-band w*64..w*64+63.
// Per q: stage A computes T_q = A_q @ X (wave's band) into LDS; stage B streams
// T_q @ B_q from LDS x wcat. Slab 6 (self) reads X rows directly from global.
__global__ __launch_bounds__(512, 2)
void k_layer(const u16* __restrict__ x, const u16* __restrict__ aq,
             const u16* __restrict__ wc, u16* __restrict__ out) {
    int b = blockIdx.x;
    int t = threadIdx.x, lane = t & 63, w = t >> 6;
    int l15 = lane & 15, lq = lane >> 4;
    const int TS = 520;                      // T row stride (u16), pad vs 512
    __shared__ __align__(16) u16 T[64 * 520];

    const u16* xb_base = x + (size_t)b * 64 * 512;
    // X as B-operand frags (q-invariant): B[k=j, col=h], h-band = w*64
    short8 xb[8];
    #pragma unroll
    for (int nt = 0; nt < 4; ++nt)
        #pragma unroll
        for (int kh = 0; kh < 2; ++kh) {
            int h = (w * 4 + nt) * 16 + l15;
            int j0 = kh * 32 + lq * 8;
            short8 v;
            #pragma unroll
            for (int jj = 0; jj < 8; ++jj)
                v[jj] = (short)xb_base[(size_t)(j0 + jj) * 512 + h];
            xb[nt * 2 + kh] = v;
        }

    floatx4 acc[16];
    #pragma unroll
    for (int i = 0; i < 16; ++i) acc[i] = (floatx4)(0.f);

    const u16* aqb   = aq + (size_t)b * 6 * 4096 + (size_t)lane * 8;
    const u16* wbase = wc + (size_t)lane * 8;

    for (int q = 0; q < 6; ++q) {
        __syncthreads();   // previous q's T reads complete
        // ---- stage A: T_q[m][h-band w]
        for (int i = 0; i < 4; ++i) {
            short8 a0 = *(const short8*)(aqb + (size_t)q * 4096 + (i * 2 + 0) * 512);
            short8 a1 = *(const short8*)(aqb + (size_t)q * 4096 + (i * 2 + 1) * 512);
            #pragma unroll
            for (int nt = 0; nt < 4; ++nt) {
                floatx4 tz = (floatx4)(0.f);
                tz = __builtin_amdgcn_mfma_f32_16x16x32_bf16(a0, xb[nt * 2 + 0], tz, 0, 0, 0);
                tz = __builtin_amdgcn_mfma_f32_16x16x32_bf16(a1, xb[nt * 2 + 1], tz, 0, 0, 0);
                int hcol = (w * 4 + nt) * 16 + l15;
                int mrow = i * 16 + lq * 4;
                #pragma unroll
                for (int reg = 0; reg < 4; ++reg)
                    T[(mrow + reg) * TS + hcol] = f2bf(tz[reg]);
            }
        }
        __syncthreads();   // T_q visible
        // ---- stage B: acc += T_q @ B_q
        for (int ks = 0; ks < 16; ++ks) {
            short8 af[4], bf[4];
            #pragma unroll
            for (int i = 0; i < 4; ++i)
                af[i] = *(const short8*)&T[(i * 16 + l15) * TS + ks * 32 + lq * 8];
            #pragma unroll
            for (int nt = 0; nt < 4; ++nt)
                bf[nt] = *(const short8*)(wbase + (size_t)(q * 16 + ks) * 16384 + (size_t)(w * 4 + nt) * 512);
            #pragma unroll
            for (int i = 0; i < 4; ++i)
                #pragma unroll
                for (int nt = 0; nt < 4; ++nt)
                    acc[i * 4 + nt] = __builtin_amdgcn_mfma_f32_16x16x32_bf16(af[i], bf[nt], acc[i * 4 + nt], 0, 0, 0);
        }
    }
    // ---- slab 6: self term, A = X rows (row-major, contiguous)
    for (int ks = 0; ks < 16; ++ks) {
        short8 af[4], bf[4];
        #pragma unroll
        for (int i = 0; i < 4; ++i)
            af[i] = *(const short8*)(xb_base + (size_t)(i * 16 + l15) * 512 + ks * 32 + lq * 8);
        #pragma unroll
        for (int nt = 0; nt < 4; ++nt)
            bf[nt] = *(const short8*)(wbase + (size_t)(96 + ks) * 16384 + (size_t)(w * 4 + nt) * 512);
        #pragma unroll
        for (int i = 0; i < 4; ++i)
            #pragma unroll
            for (int nt = 0; nt < 4; ++nt)
                acc[i * 4 + nt] = __builtin_amdgcn_mfma_f32_16x16x32_bf16(af[i], bf[nt], acc[i * 4 + nt], 0, 0, 0);
    }
    // ---- epilogue: relu, y[m = i*16+lq*4+reg][n = (w*4+nt)*16+l15]
    #pragma unroll
    for (int i = 0; i < 4; ++i)
        #pragma unroll
        for (int nt = 0; nt < 4; ++nt) {
            int n = (w * 4 + nt) * 16 + l15;
            int m0 = i * 16 + lq * 4;
            #pragma unroll
            for (int reg = 0; reg < 4; ++reg)
                out[((size_t)b * 64 + m0 + reg) * 512 + n] = f2bf(fmaxf(acc[i * 4 + nt][reg], 0.f));
        }
}

// ---------------------------------------------------------------------------
// Final RGCN layer: only output rows 48..63 needed (i = 3).
// mode 1: sigmoid rows 58..61 -> o16 ; mode 2: sigmoid rows 60,62 -> o32 slots.
__global__ __launch_bounds__(512, 2)
void k_layer_last(const u16* __restrict__ x, const u16* __restrict__ aq,
                  const u16* __restrict__ wc, int mode,
                  u16* __restrict__ o16, float* __restrict__ o32) {
    int b = blockIdx.x;
    int t = threadIdx.x, lane = t & 63, w = t >> 6;
    int l15 = lane & 15, lq = lane >> 4;
    const int TS = 520;
    __shared__ __align__(16) u16 T[16 * 520];

    const u16* xb_base = x + (size_t)b * 64 * 512;
    short8 xb[8];
    #pragma unroll
    for (int nt = 0; nt < 4; ++nt)
        #pragma unroll
        for (int kh = 0; kh < 2; ++kh) {
            int h = (w * 4 + nt) * 16 + l15;
            int j0 = kh * 32 + lq * 8;
            short8 v;
            #pragma unroll
            for (int jj = 0; jj < 8; ++jj)
                v[jj] = (short)xb_base[(size_t)(j0 + jj) * 512 + h];
            xb[nt * 2 + kh] = v;
        }

    floatx4 acc[4];
    #pragma unroll
    for (int i = 0; i < 4; ++i) acc[i] = (floatx4)(0.f);

    const u16* aqb   = aq + (size_t)b * 6 * 4096 + (size_t)lane * 8;
    const u16* wbase = wc + (size_t)lane * 8;

    for (int q = 0; q < 6; ++q) {
        __syncthreads();
        // stage A: rows 48..63 only (frag i=3: f = 6,7)
        {
            short8 a0 = *(const short8*)(aqb + (size_t)q * 4096 + 6 * 512);
            short8 a1 = *(const short8*)(aqb + (size_t)q * 4096 + 7 * 512);
            #pragma unroll
            for (int nt = 0; nt < 4; ++nt) {
                floatx4 tz = (floatx4)(0.f);
                tz = __builtin_amdgcn_mfma_f32_16x16x32_bf16(a0, xb[nt * 2 + 0], tz, 0, 0, 0);
                tz = __builtin_amdgcn_mfma_f32_16x16x32_bf16(a1, xb[nt * 2 + 1], tz, 0, 0, 0);
                int hcol = (w * 4 + nt) * 16 + l15;
                int mrow = lq * 4;
                #pragma unroll
                for (int reg = 0; reg < 4; ++reg)
                    T[(mrow + reg) * TS + hcol] = f2bf(tz[reg]);
            }
        }
        __syncthreads();
        // stage B
        for (int ks = 0; ks < 16; ++ks) {
            short8 af = *(const short8*)&T[l15 * TS + ks * 32 + lq * 8];
            #pragma unroll
            for (int nt = 0; nt < 4; ++nt) {
                short8 bf = *(const short8*)(wbase + (size_t)(q * 16 + ks) * 16384 + (size_t)(w * 4 + nt) * 512);
                acc[nt] = __builtin_amdgcn_mfma_f32_16x16x32_bf16(af, bf, acc[nt], 0, 0, 0);
            }
        }
    }
    // slab 6: self, X rows 48..63
    for (int ks = 0; ks < 16; ++ks) {
        short8 af = *(const short8*)(xb_base + (size_t)(48 + l15) * 512 + ks * 32 + lq * 8);
        #pragma unroll
        for (int nt = 0; nt < 4; ++nt) {
            short8 bf = *(const short8*)(wbase + (size_t)(96 + ks) * 16384 + (size_t)(w * 4 + nt) * 512);
            acc[nt] = __builtin_amdgcn_mfma_f32_16x16x32_bf16(af, bf, acc[nt], 0, 0, 0);
        }
    }
    // epilogue: m = 48 + lq*4 + reg
    #pragma unroll
    for (int nt = 0; nt < 4; ++nt) {
        int n = (w * 4 + nt) * 16 + l15;
        #pragma unroll
        for (int reg = 0; reg < 4; ++reg) {
            int m = 48 + lq * 4 + reg;
            float v = acc[nt][reg];
            if (mode == 1) {
                if (m >= 58 && m <= 61)
                    o16[((size_t)b * 64 + m) * 512 + n] = f2bf(1.f / (1.f + __expf(-v)));
            } else {
                if (m == 60 || m == 62) {
                    int slot = (m == 60) ? (b * 2) : (b * 2 + 1);
                    o32[(size_t)slot * 512 + n] = 1.f / (1.f + __expf(-v));
                }
            }
        }
    }
}

// logits = [black|white] @ type_W^T + type_b  (unchanged, validated)
__global__ void k_final(const float* __restrict__ t2, const float* __restrict__ tW,
                        const float* __restrict__ tb, float* __restrict__ outp) {
    int b = blockIdx.x, l = threadIdx.x;   // 64 threads
    float a[11];
    #pragma unroll
    for (int j = 0; j < 11; ++j) a[j] = 0.f;
    for (int it = 0; it < 16; ++it) {
        int h = it * 64 + l;
        float c = (h < 512) ? t2[(b * 2 + 1) * 512 + h] : t2[(b * 2 + 0) * 512 + (h - 512)];
        #pragma unroll
        for (int j = 0; j < 11; ++j) a[j] += c * tW[j * 1024 + h];
    }
    #pragma unroll
    for (int j = 0; j < 11; ++j) {
        float v = a[j];
        for (int off = 32; off > 0; off >>= 1) v += __shfl_down(v, off, 64);
        if (l == 0) outp[b * 11 + j] = v + tb[j];
    }
}

// ---------------------------------------------------------------------------
extern "C" void kernel_launch(void* const* d_in, const int* in_sizes, int n_in,
                              void* d_out, int out_size, void* d_ws, size_t ws_size,
                              hipStream_t stream) {
    const int*   player = (const int*)d_in[0];
    const float* enc    = (const float*)d_in[2];
    const int*   adjm   = (const int*)d_in[3];
    const float* pAx    = (const float*)d_in[4];
    const float* pAy    = (const float*)d_in[5];
    const float* pBx    = (const float*)d_in[6];
    const float* pBy    = (const float*)d_in[7];
    const float* emb    = (const float*)d_in[8];
    const float* cW     = (const float*)d_in[9];
    const float* cb     = (const float*)d_in[10];
    const float* inW    = (const float*)d_in[11];
    const float* inb    = (const float*)d_in[12];
    const float* basis0 = (const float*)d_in[13];
    const float* comb0  = (const float*)d_in[14];
    const float* self0  = (const float*)d_in[15];
    const float* basis1 = (const float*)d_in[16];
    const float* comb1  = (const float*)d_in[17];
    const float* self1  = (const float*)d_in[18];
    const float* typeW  = (const float*)d_in[19];
    const float* typeb  = (const float*)d_in[20];

    char* ws = (char*)d_ws;
    size_t off = 0;
    auto alloc = [&](size_t bytes) -> void* {
        void* p = ws + off;
        off = (off + bytes + 255) & ~(size_t)255;
        return p;
    };
    // Workspace (peak ~83 MB, under proven 89 MB):
    //   mi1 region: mi1 (prep..layer1) -> x12b (layer3..layer4)
    //   x12 region: x12 (layer1..layer2) -> t2 (layer4..final)
    //   aq region: [set0|set1] variant0 (..layer2) -> variant1 (..layer4)
    u16* mi1   = (u16*)alloc(256UL * 64 * 512 * 2);
    u16* mi2   = (u16*)alloc(256UL * 64 * 512 * 2);
    u16* x12   = (u16*)alloc(256UL * 64 * 512 * 2);
    u16* aqbuf = (u16*)alloc(2UL * AQ_SETSTRIDE * 2);
    u16* wcat0 = (u16*)alloc(3584UL * 512 * 2);
    u16* wcat1 = (u16*)alloc(3584UL * 512 * 2);
    u16* x12b  = mi1;             // mi1 dead after layer 1
    float* t2  = (float*)x12;     // x12 dead after layer 2
    u16* aq0   = aqbuf;
    u16* aq1   = aqbuf + AQ_SETSTRIDE;

    k_wcat<<<448, 256, 0, stream>>>(basis0, self0, wcat0);
    k_wcat<<<448, 256, 0, stream>>>(basis1, self1, wcat1);
    k_adjq<<<256, 256, 0, stream>>>(adjm, comb0, comb1, aqbuf, 0);
    k_prep<<<256, 256, 0, stream>>>(player, pAx, pAy, pBx, pBy, emb, cW, cb, inW, inb, mi1, mi2);
    k_cast<<<3840, 256, 0, stream>>>(enc, mi1, mi2);

    // rgcn pass 1
    k_layer<<<256, 512, 0, stream>>>(mi1, aq0, wcat0, x12);
    k_layer_last<<<256, 512, 0, stream>>>(x12, aq1, wcat1, 1, mi2, nullptr);
    // regenerate weighted adjacency for the pruned pass-2 graph
    k_adjq<<<256, 256, 0, stream>>>(adjm, comb0, comb1, aqbuf, 1);
    // rgcn pass 2
    k_layer<<<256, 512, 0, stream>>>(mi2, aq0, wcat0, x12b);
    k_layer_last<<<256, 512, 0, stream>>>(x12b, aq1, wcat1, 2, nullptr, t2);

    k_final<<<256, 64, 0, stream>>>(t2, typeW, typeb, (float*)d_out);
}

// Round 4
// 624.442 us; speedup vs baseline: 1.4432x; 1.1306x over previous
//
#include <hip/hip_runtime.h>
#include <hip/hip_bf16.h>

typedef unsigned short u16;
typedef unsigned long long u64;
typedef __attribute__((ext_vector_type(4))) short short4v;
typedef __attribute__((ext_vector_type(8))) short short8;
typedef __attribute__((ext_vector_type(4))) float floatx4;

__device__ __forceinline__ u16 f2bf(float f) {
    union { float f; unsigned u; } v; v.f = f;
    unsigned r = v.u + 0x7FFF + ((v.u >> 16) & 1);
    return (u16)(r >> 16);
}

// ---------------------------------------------------------------------------
// Wcat stack: 7 slabs [B_0..B_5, selfW^T], K = 3584, fragment layout validated
// element (k,n) at: (k>>5)*16384 + (n>>4)*512 + ((k>>3)&3)*128 + (n&15)*8 + (k&7)
// value = k<3072 ? basis[k>>9][k&511][n] : selfW[n][k-3072]
__global__ void k_wcat(const float* __restrict__ basis, const float* __restrict__ selfW,
                       u16* __restrict__ wf) {
    int bi = blockIdx.x, t = threadIdx.x;
    int kr = t >> 7;             // 0..1
    int nb = (t & 127) * 4;      // n base
    for (int it = 0; it < 4; ++it) {
        int k = bi * 8 + it * 2 + kr;     // 0..3583 over grid 448
        float v0, v1, v2, v3;
        if (k < 3072) {
            int q = k >> 9, h = k & 511;
            const float4 bz = *(const float4*)(basis + ((size_t)(q * 512 + h)) * 512 + nb);
            v0 = bz.x; v1 = bz.y; v2 = bz.z; v3 = bz.w;
        } else {
            int kk = k - 3072;
            v0 = selfW[(size_t)(nb + 0) * 512 + kk];
            v1 = selfW[(size_t)(nb + 1) * 512 + kk];
            v2 = selfW[(size_t)(nb + 2) * 512 + kk];
            v3 = selfW[(size_t)(nb + 3) * 512 + kk];
        }
        float vv[4] = {v0, v1, v2, v3};
        for (int i = 0; i < 4; ++i) {
            int n = nb + i;
            wf[(size_t)(k >> 5) * 16384 + (n >> 4) * 512 + ((k >> 3) & 3) * 128 + (n & 15) * 8 + (k & 7)] = f2bf(vv[i]);
        }
    }
}

// ---------------------------------------------------------------------------
// Row masks via coalesced row reads + wave ballot. One wave per (b, r).
// m0: variant-0 (raw 62x62) masks; m1: variant-1 (remapped + parity) masks.
// m[(b*12+r)*64 + n] = 64-bit row mask.
__global__ void k_masks(const int* __restrict__ A, u64* __restrict__ m0, u64* __restrict__ m1) {
    int bi = blockIdx.x;          // b*12 + r
    int b = bi / 12, r = bi % 12;
    const int* Ab = A + (size_t)(b * 13 + (r + 1)) * 62 * 62;
    int lane = threadIdx.x;       // 0..63
    u64 my0 = 0, my1 = 0;
    for (int n = 0; n < 64; ++n) {
        // coalesced row read (row oi = (n==62)?63:n maps to same data; oi>=62 -> 0)
        int raw = 0;
        if (n < 62 && lane < 62) raw = (Ab[n * 62 + lane] != 0) ? 1 : 0;
        // variant 0: bit lane of row n
        u64 b0 = __ballot(raw != 0);
        // variant 1: oi = (n==62)?63:n, oj = (lane==62)?63:lane, cols 0..62
        int v1 = 0;
        if (n < 63 && lane < 63) {
            int oi = (n == 62) ? 63 : n;
            int oj = (lane == 62) ? 63 : lane;
            v1 = (oi < 62 && oj < 62) ? raw : 0;
            int lo = (oi < oj) ? oi : oj, hi = (oi < oj) ? oj : oi;
            if (hi == lo + 2) {
                int p = (lo >> 1) & 1;
                int chp = ((lo & 1) == 0) ? (p ? 12 : 11) : (p ? 11 : 12);
                if (r + 1 == chp) v1 = 1;
            }
        }
        u64 b1 = __ballot(v1 != 0);
        if (lane == n) { my0 = b0; my1 = b1; }
    }
    m0[(size_t)bi * 64 + lane] = my0;
    m1[(size_t)bi * 64 + lane] = my1;
}

// ---------------------------------------------------------------------------
// Weighted adjacency expansion: A_q = sum_r comb[r][q] * adj_r -> bf16 frags.
//   aq[set][(b*6+q)*4096 + f*512 + lane*8 + j]
//   value = A_q[row = (f>>1)*16 + (lane&15), col = (f&1)*32 + (lane>>4)*8 + j]
// Grid = b*8; block handles 512 positions (2 ii-chunks). Masks from k_masks.
#define AQ_SETSTRIDE (256UL * 6 * 4096)
__global__ void k_aqexp(const u64* __restrict__ msk, const float* __restrict__ comb0,
                        const float* __restrict__ comb1, u16* __restrict__ aq) {
    int b = blockIdx.x >> 3, sp = blockIdx.x & 7;
    int t = threadIdx.x;
    __shared__ u64 sm[12 * 64];
    __shared__ float cmb[2][12][6];
    if (t < 72) { cmb[0][t / 6][t % 6] = comb0[t]; cmb[1][t / 6][t % 6] = comb1[t]; }
    for (int i = t; i < 768; i += 256) sm[i] = msk[(size_t)b * 768 + i];
    __syncthreads();
    #pragma unroll
    for (int ii2 = 0; ii2 < 2; ++ii2) {
        int pos = (sp * 2 + ii2) * 256 + t;
        int f = pos >> 9, lane = (pos >> 3) & 63, j = pos & 7;
        int row = ((f >> 1) << 4) + (lane & 15);
        int mb  = ((f & 1) << 5) + ((lane >> 4) << 3) + j;
        float bits[12];
        #pragma unroll
        for (int r = 0; r < 12; ++r) bits[r] = (float)((sm[r * 64 + row] >> mb) & 1ull);
        #pragma unroll
        for (int s = 0; s < 2; ++s)
            #pragma unroll
            for (int q = 0; q < 6; ++q) {
                float v = 0.f;
                #pragma unroll
                for (int r = 0; r < 12; ++r) v += bits[r] * cmb[s][r][q];
                aq[(size_t)s * AQ_SETSTRIDE + ((size_t)b * 6 + q) * 4096 + pos] = f2bf(v);
            }
    }
}

// ---------------------------------------------------------------------------
// initial embedding -> mi1 rows 60..63 ; mi2 rows 62,63  (unchanged, validated)
__global__ void k_prep(const int* __restrict__ player,
                       const float* __restrict__ pAx, const float* __restrict__ pAy,
                       const float* __restrict__ pBx, const float* __restrict__ pBy,
                       const float* __restrict__ emb, const float* __restrict__ cW,
                       const float* __restrict__ cb, const float* __restrict__ inW,
                       const float* __restrict__ inb,
                       u16* __restrict__ mi1, u16* __restrict__ mi2) {
    int b = blockIdx.x, t = threadIdx.x;
    __shared__ float feat[2][64];
    if (t < 64) {
        int j = t >> 5, d = t & 31;
        float X = j ? pBx[b] : pAx[b];
        float Y = j ? pBy[b] : pAy[b];
        feat[j][d] = fmaxf(cW[d * 2] * X + cW[d * 2 + 1] * Y + cb[d], 0.f);
        feat[j][32 + d] = emb[player[b * 2 + j] * 32 + d];
    }
    __syncthreads();
    for (int h = t; h < 512; h += 256) {
        float a0 = inb[h], a1 = inb[h];
        const float* wrow = inW + h * 64;
        #pragma unroll
        for (int d = 0; d < 64; ++d) {
            float wv = wrow[d];
            a0 += wv * feat[0][d];
            a1 += wv * feat[1][d];
        }
        u16 v0 = f2bf(a0), v1 = f2bf(a1);
        size_t base = (size_t)b * 64 * 512;
        mi1[base + 60 * 512 + h] = v0;
        mi1[base + 61 * 512 + h] = v1;
        mi1[base + 62 * 512 + h] = 0;
        mi1[base + 63 * 512 + h] = 0;
        mi2[base + 62 * 512 + h] = v1;
        mi2[base + 63 * 512 + h] = 0;
    }
}

// enc f32 -> mi1 rows 0..59 ; mi2 rows 0..57  (unchanged, validated)
__global__ void k_cast(const float* __restrict__ enc, u16* __restrict__ mi1, u16* __restrict__ mi2) {
    long long e = ((long long)blockIdx.x * 256 + threadIdx.x) * 8;
    if (e >= 256LL * 60 * 512) return;
    int b = (int)(e / (60 * 512));
    int rm = (int)(e % (60 * 512));
    int n = rm / 512, h = rm % 512;
    for (int i = 0; i < 8; ++i) {
        u16 v = f2bf(enc[e + i]);
        mi1[((size_t)b * 64 + n) * 512 + h + i] = v;
        if (n < 58) mi2[((size_t)b * 64 + n) * 512 + h + i] = v;
    }
}

// ---------------------------------------------------------------------------
// Full RGCN layer via basis decomposition (unchanged, validated round 3):
//   Y = relu( sum_q (A_q @ X) @ B_q  +  X @ selfW^T )
__global__ __launch_bounds__(512, 2)
void k_layer(const u16* __restrict__ x, const u16* __restrict__ aq,
             const u16* __restrict__ wc, u16* __restrict__ out) {
    int b = blockIdx.x;
    int t = threadIdx.x, lane = t & 63, w = t >> 6;
    int l15 = lane & 15, lq = lane >> 4;
    const int TS = 520;                      // T row stride (u16), pad vs 512
    __shared__ __align__(16) u16 T[64 * 520];

    const u16* xb_base = x + (size_t)b * 64 * 512;
    // X as B-operand frags (q-invariant): B[k=j, col=h], h-band = w*64
    short8 xb[8];
    #pragma unroll
    for (int nt = 0; nt < 4; ++nt)
        #pragma unroll
        for (int kh = 0; kh < 2; ++kh) {
            int h = (w * 4 + nt) * 16 + l15;
            int j0 = kh * 32 + lq * 8;
            short8 v;
            #pragma unroll
            for (int jj = 0; jj < 8; ++jj)
                v[jj] = (short)xb_base[(size_t)(j0 + jj) * 512 + h];
            xb[nt * 2 + kh] = v;
        }

    floatx4 acc[16];
    #pragma unroll
    for (int i = 0; i < 16; ++i) acc[i] = (floatx4)(0.f);

    const u16* aqb   = aq + (size_t)b * 6 * 4096 + (size_t)lane * 8;
    const u16* wbase = wc + (size_t)lane * 8;

    for (int q = 0; q < 6; ++q) {
        __syncthreads();   // previous q's T reads complete
        // ---- stage A: T_q[m][h-band w]
        for (int i = 0; i < 4; ++i) {
            short8 a0 = *(const short8*)(aqb + (size_t)q * 4096 + (i * 2 + 0) * 512);
            short8 a1 = *(const short8*)(aqb + (size_t)q * 4096 + (i * 2 + 1) * 512);
            #pragma unroll
            for (int nt = 0; nt < 4; ++nt) {
                floatx4 tz = (floatx4)(0.f);
                tz = __builtin_amdgcn_mfma_f32_16x16x32_bf16(a0, xb[nt * 2 + 0], tz, 0, 0, 0);
                tz = __builtin_amdgcn_mfma_f32_16x16x32_bf16(a1, xb[nt * 2 + 1], tz, 0, 0, 0);
                int hcol = (w * 4 + nt) * 16 + l15;
                int mrow = i * 16 + lq * 4;
                #pragma unroll
                for (int reg = 0; reg < 4; ++reg)
                    T[(mrow + reg) * TS + hcol] = f2bf(tz[reg]);
            }
        }
        __syncthreads();   // T_q visible
        // ---- stage B: acc += T_q @ B_q
        for (int ks = 0; ks < 16; ++ks) {
            short8 af[4], bf[4];
            #pragma unroll
            for (int i = 0; i < 4; ++i)
                af[i] = *(const short8*)&T[(i * 16 + l15) * TS + ks * 32 + lq * 8];
            #pragma unroll
            for (int nt = 0; nt < 4; ++nt)
                bf[nt] = *(const short8*)(wbase + (size_t)(q * 16 + ks) * 16384 + (size_t)(w * 4 + nt) * 512);
            #pragma unroll
            for (int i = 0; i < 4; ++i)
                #pragma unroll
                for (int nt = 0; nt < 4; ++nt)
                    acc[i * 4 + nt] = __builtin_amdgcn_mfma_f32_16x16x32_bf16(af[i], bf[nt], acc[i * 4 + nt], 0, 0, 0);
        }
    }
    // ---- slab 6: self term, A = X rows (row-major, contiguous)
    for (int ks = 0; ks < 16; ++ks) {
        short8 af[4], bf[4];
        #pragma unroll
        for (int i = 0; i < 4; ++i)
            af[i] = *(const short8*)(xb_base + (size_t)(i * 16 + l15) * 512 + ks * 32 + lq * 8);
        #pragma unroll
        for (int nt = 0; nt < 4; ++nt)
            bf[nt] = *(const short8*)(wbase + (size_t)(96 + ks) * 16384 + (size_t)(w * 4 + nt) * 512);
        #pragma unroll
        for (int i = 0; i < 4; ++i)
            #pragma unroll
            for (int nt = 0; nt < 4; ++nt)
                acc[i * 4 + nt] = __builtin_amdgcn_mfma_f32_16x16x32_bf16(af[i], bf[nt], acc[i * 4 + nt], 0, 0, 0);
    }
    // ---- epilogue: relu, y[m = i*16+lq*4+reg][n = (w*4+nt)*16+l15]
    #pragma unroll
    for (int i = 0; i < 4; ++i)
        #pragma unroll
        for (int nt = 0; nt < 4; ++nt) {
            int n = (w * 4 + nt) * 16 + l15;
            int m0 = i * 16 + lq * 4;
            #pragma unroll
            for (int reg = 0; reg < 4; ++reg)
                out[((size_t)b * 64 + m0 + reg) * 512 + n] = f2bf(fmaxf(acc[i * 4 + nt][reg], 0.f));
        }
}

// ---------------------------------------------------------------------------
// Final RGCN layer: only output rows 48..63 needed (unchanged, validated).
__global__ __launch_bounds__(512, 2)
void k_layer_last(const u16* __restrict__ x, const u16* __restrict__ aq,
                  const u16* __restrict__ wc, int mode,
                  u16* __restrict__ o16, float* __restrict__ o32) {
    int b = blockIdx.x;
    int t = threadIdx.x, lane = t & 63, w = t >> 6;
    int l15 = lane & 15, lq = lane >> 4;
    const int TS = 520;
    __shared__ __align__(16) u16 T[16 * 520];

    const u16* xb_base = x + (size_t)b * 64 * 512;
    short8 xb[8];
    #pragma unroll
    for (int nt = 0; nt < 4; ++nt)
        #pragma unroll
        for (int kh = 0; kh < 2; ++kh) {
            int h = (w * 4 + nt) * 16 + l15;
            int j0 = kh * 32 + lq * 8;
            short8 v;
            #pragma unroll
            for (int jj = 0; jj < 8; ++jj)
                v[jj] = (short)xb_base[(size_t)(j0 + jj) * 512 + h];
            xb[nt * 2 + kh] = v;
        }

    floatx4 acc[4];
    #pragma unroll
    for (int i = 0; i < 4; ++i) acc[i] = (floatx4)(0.f);

    const u16* aqb   = aq + (size_t)b * 6 * 4096 + (size_t)lane * 8;
    const u16* wbase = wc + (size_t)lane * 8;

    for (int q = 0; q < 6; ++q) {
        __syncthreads();
        // stage A: rows 48..63 only (frag i=3: f = 6,7)
        {
            short8 a0 = *(const short8*)(aqb + (size_t)q * 4096 + 6 * 512);
            short8 a1 = *(const short8*)(aqb + (size_t)q * 4096 + 7 * 512);
            #pragma unroll
            for (int nt = 0; nt < 4; ++nt) {
                floatx4 tz = (floatx4)(0.f);
                tz = __builtin_amdgcn_mfma_f32_16x16x32_bf16(a0, xb[nt * 2 + 0], tz, 0, 0, 0);
                tz = __builtin_amdgcn_mfma_f32_16x16x32_bf16(a1, xb[nt * 2 + 1], tz, 0, 0, 0);
                int hcol = (w * 4 + nt) * 16 + l15;
                int mrow = lq * 4;
                #pragma unroll
                for (int reg = 0; reg < 4; ++reg)
                    T[(mrow + reg) * TS + hcol] = f2bf(tz[reg]);
            }
        }
        __syncthreads();
        // stage B
        for (int ks = 0; ks < 16; ++ks) {
            short8 af = *(const short8*)&T[l15 * TS + ks * 32 + lq * 8];
            #pragma unroll
            for (int nt = 0; nt < 4; ++nt) {
                short8 bf = *(const short8*)(wbase + (size_t)(q * 16 + ks) * 16384 + (size_t)(w * 4 + nt) * 512);
                acc[nt] = __builtin_amdgcn_mfma_f32_16x16x32_bf16(af, bf, acc[nt], 0, 0, 0);
            }
        }
    }
    // slab 6: self, X rows 48..63
    for (int ks = 0; ks < 16; ++ks) {
        short8 af = *(const short8*)(xb_base + (size_t)(48 + l15) * 512 + ks * 32 + lq * 8);
        #pragma unroll
        for (int nt = 0; nt < 4; ++nt) {
            short8 bf = *(const short8*)(wbase + (size_t)(96 + ks) * 16384 + (size_t)(w * 4 + nt) * 512);
            acc[nt] = __builtin_amdgcn_mfma_f32_16x16x32_bf16(af, bf, acc[nt], 0, 0, 0);
        }
    }
    // epilogue: m = 48 + lq*4 + reg
    #pragma unroll
    for (int nt = 0; nt < 4; ++nt) {
        int n = (w * 4 + nt) * 16 + l15;
        #pragma unroll
        for (int reg = 0; reg < 4; ++reg) {
            int m = 48 + lq * 4 + reg;
            float v = acc[nt][reg];
            if (mode == 1) {
                if (m >= 58 && m <= 61)
                    o16[((size_t)b * 64 + m) * 512 + n] = f2bf(1.f / (1.f + __expf(-v)));
            } else {
                if (m == 60 || m == 62) {
                    int slot = (m == 60) ? (b * 2) : (b * 2 + 1);
                    o32[(size_t)slot * 512 + n] = 1.f / (1.f + __expf(-v));
                }
            }
        }
    }
}

// logits = [black|white] @ type_W^T + type_b  (unchanged, validated)
__global__ void k_final(const float* __restrict__ t2, const float* __restrict__ tW,
                        const float* __restrict__ tb, float* __restrict__ outp) {
    int b = blockIdx.x, l = threadIdx.x;   // 64 threads
    float a[11];
    #pragma unroll
    for (int j = 0; j < 11; ++j) a[j] = 0.f;
    for (int it = 0; it < 16; ++it) {
        int h = it * 64 + l;
        float c = (h < 512) ? t2[(b * 2 + 1) * 512 + h] : t2[(b * 2 + 0) * 512 + (h - 512)];
        #pragma unroll
        for (int j = 0; j < 11; ++j) a[j] += c * tW[j * 1024 + h];
    }
    #pragma unroll
    for (int j = 0; j < 11; ++j) {
        float v = a[j];
        for (int off = 32; off > 0; off >>= 1) v += __shfl_down(v, off, 64);
        if (l == 0) outp[b * 11 + j] = v + tb[j];
    }
}

// ---------------------------------------------------------------------------
extern "C" void kernel_launch(void* const* d_in, const int* in_sizes, int n_in,
                              void* d_out, int out_size, void* d_ws, size_t ws_size,
                              hipStream_t stream) {
    const int*   player = (const int*)d_in[0];
    const float* enc    = (const float*)d_in[2];
    const int*   adjm   = (const int*)d_in[3];
    const float* pAx    = (const float*)d_in[4];
    const float* pAy    = (const float*)d_in[5];
    const float* pBx    = (const float*)d_in[6];
    const float* pBy    = (const float*)d_in[7];
    const float* emb    = (const float*)d_in[8];
    const float* cW     = (const float*)d_in[9];
    const float* cb     = (const float*)d_in[10];
    const float* inW    = (const float*)d_in[11];
    const float* inb    = (const float*)d_in[12];
    const float* basis0 = (const float*)d_in[13];
    const float* comb0  = (const float*)d_in[14];
    const float* self0  = (const float*)d_in[15];
    const float* basis1 = (const float*)d_in[16];
    const float* comb1  = (const float*)d_in[17];
    const float* self1  = (const float*)d_in[18];
    const float* typeW  = (const float*)d_in[19];
    const float* typeb  = (const float*)d_in[20];

    char* ws = (char*)d_ws;
    size_t off = 0;
    auto alloc = [&](size_t bytes) -> void* {
        void* p = ws + off;
        off = (off + bytes + 255) & ~(size_t)255;
        return p;
    };
    // Workspace (peak ~86.5 MB, under proven 89 MB):
    //   mi1 region: mi1 (prep..layer1) -> x12b (layer3..layer4)
    //   x12 region: x12 (layer1..layer2) -> t2 (layer4..final)
    //   aq region: [set0|set1] variant0 (..layer2) -> variant1 (..layer4)
    u16* mi1   = (u16*)alloc(256UL * 64 * 512 * 2);
    u16* mi2   = (u16*)alloc(256UL * 64 * 512 * 2);
    u16* x12   = (u16*)alloc(256UL * 64 * 512 * 2);
    u16* aqbuf = (u16*)alloc(2UL * AQ_SETSTRIDE * 2);
    u16* wcat0 = (u16*)alloc(3584UL * 512 * 2);
    u16* wcat1 = (u16*)alloc(3584UL * 512 * 2);
    u64* mm0   = (u64*)alloc(256UL * 12 * 64 * 8);
    u64* mm1   = (u64*)alloc(256UL * 12 * 64 * 8);
    u16* x12b  = mi1;             // mi1 dead after layer 1
    float* t2  = (float*)x12;     // x12 dead after layer 2
    u16* aq0   = aqbuf;
    u16* aq1   = aqbuf + AQ_SETSTRIDE;

    k_wcat<<<448, 256, 0, stream>>>(basis0, self0, wcat0);
    k_wcat<<<448, 256, 0, stream>>>(basis1, self1, wcat1);
    k_masks<<<3072, 64, 0, stream>>>(adjm, mm0, mm1);
    k_aqexp<<<2048, 256, 0, stream>>>(mm0, comb0, comb1, aqbuf);
    k_prep<<<256, 256, 0, stream>>>(player, pAx, pAy, pBx, pBy, emb, cW, cb, inW, inb, mi1, mi2);
    k_cast<<<3840, 256, 0, stream>>>(enc, mi1, mi2);

    // rgcn pass 1
    k_layer<<<256, 512, 0, stream>>>(mi1, aq0, wcat0, x12);
    k_layer_last<<<256, 512, 0, stream>>>(x12, aq1, wcat1, 1, mi2, nullptr);
    // regenerate weighted adjacency for the pruned pass-2 graph
    k_aqexp<<<2048, 256, 0, stream>>>(mm1, comb0, comb1, aqbuf);
    // rgcn pass 2
    k_layer<<<256, 512, 0, stream>>>(mi2, aq0, wcat0, x12b);
    k_layer_last<<<256, 512, 0, stream>>>(x12b, aq1, wcat1, 2, nullptr, t2);

    k_final<<<256, 64, 0, stream>>>(t2, typeW, typeb, (float*)d_out);
}

// Round 5
// 605.698 us; speedup vs baseline: 1.4878x; 1.0309x over previous
//
#include <hip/hip_runtime.h>
#include <hip/hip_bf16.h>

typedef unsigned short u16;
typedef unsigned long long u64;
typedef __attribute__((ext_vector_type(4))) short short4v;
typedef __attribute__((ext_vector_type(8))) short short8;
typedef __attribute__((ext_vector_type(4))) float floatx4;

__device__ __forceinline__ u16 f2bf(float f) {
    union { float f; unsigned u; } v; v.f = f;
    unsigned r = v.u + 0x7FFF + ((v.u >> 16) & 1);
    return (u16)(r >> 16);
}

// ---------------------------------------------------------------------------
// Wcat stack: 7 slabs [B_0..B_5, selfW^T], K = 3584, fragment layout validated
// element (k,n) at: (k>>5)*16384 + (n>>4)*512 + ((k>>3)&3)*128 + (n&15)*8 + (k&7)
// value = k<3072 ? basis[k>>9][k&511][n] : selfW[n][k-3072]
__global__ void k_wcat(const float* __restrict__ basis, const float* __restrict__ selfW,
                       u16* __restrict__ wf) {
    int bi = blockIdx.x, t = threadIdx.x;
    int kr = t >> 7;             // 0..1
    int nb = (t & 127) * 4;      // n base
    for (int it = 0; it < 4; ++it) {
        int k = bi * 8 + it * 2 + kr;     // 0..3583 over grid 448
        float v0, v1, v2, v3;
        if (k < 3072) {
            int q = k >> 9, h = k & 511;
            const float4 bz = *(const float4*)(basis + ((size_t)(q * 512 + h)) * 512 + nb);
            v0 = bz.x; v1 = bz.y; v2 = bz.z; v3 = bz.w;
        } else {
            int kk = k - 3072;
            v0 = selfW[(size_t)(nb + 0) * 512 + kk];
            v1 = selfW[(size_t)(nb + 1) * 512 + kk];
            v2 = selfW[(size_t)(nb + 2) * 512 + kk];
            v3 = selfW[(size_t)(nb + 3) * 512 + kk];
        }
        float vv[4] = {v0, v1, v2, v3};
        for (int i = 0; i < 4; ++i) {
            int n = nb + i;
            wf[(size_t)(k >> 5) * 16384 + (n >> 4) * 512 + ((k >> 3) & 3) * 128 + (n & 15) * 8 + (k & 7)] = f2bf(vv[i]);
        }
    }
}

// ---------------------------------------------------------------------------
// Row masks via coalesced row reads + wave ballot. One wave per (b, r).
__global__ void k_masks(const int* __restrict__ A, u64* __restrict__ m0, u64* __restrict__ m1) {
    int bi = blockIdx.x;          // b*12 + r
    int b = bi / 12, r = bi % 12;
    const int* Ab = A + (size_t)(b * 13 + (r + 1)) * 62 * 62;
    int lane = threadIdx.x;       // 0..63
    u64 my0 = 0, my1 = 0;
    for (int n = 0; n < 64; ++n) {
        int raw = 0;
        if (n < 62 && lane < 62) raw = (Ab[n * 62 + lane] != 0) ? 1 : 0;
        u64 b0 = __ballot(raw != 0);
        int v1 = 0;
        if (n < 63 && lane < 63) {
            int oi = (n == 62) ? 63 : n;
            int oj = (lane == 62) ? 63 : lane;
            v1 = (oi < 62 && oj < 62) ? raw : 0;
            int lo = (oi < oj) ? oi : oj, hi = (oi < oj) ? oj : oi;
            if (hi == lo + 2) {
                int p = (lo >> 1) & 1;
                int chp = ((lo & 1) == 0) ? (p ? 12 : 11) : (p ? 11 : 12);
                if (r + 1 == chp) v1 = 1;
            }
        }
        u64 b1 = __ballot(v1 != 0);
        if (lane == n) { my0 = b0; my1 = b1; }
    }
    m0[(size_t)bi * 64 + lane] = my0;
    m1[(size_t)bi * 64 + lane] = my1;
}

// ---------------------------------------------------------------------------
// Weighted adjacency expansion: A_q = sum_r comb[r][q] * adj_r -> bf16 frags.
#define AQ_SETSTRIDE (256UL * 6 * 4096)
__global__ void k_aqexp(const u64* __restrict__ msk, const float* __restrict__ comb0,
                        const float* __restrict__ comb1, u16* __restrict__ aq) {
    int b = blockIdx.x >> 3, sp = blockIdx.x & 7;
    int t = threadIdx.x;
    __shared__ u64 sm[12 * 64];
    __shared__ float cmb[2][12][6];
    if (t < 72) { cmb[0][t / 6][t % 6] = comb0[t]; cmb[1][t / 6][t % 6] = comb1[t]; }
    for (int i = t; i < 768; i += 256) sm[i] = msk[(size_t)b * 768 + i];
    __syncthreads();
    #pragma unroll
    for (int ii2 = 0; ii2 < 2; ++ii2) {
        int pos = (sp * 2 + ii2) * 256 + t;
        int f = pos >> 9, lane = (pos >> 3) & 63, j = pos & 7;
        int row = ((f >> 1) << 4) + (lane & 15);
        int mb  = ((f & 1) << 5) + ((lane >> 4) << 3) + j;
        float bits[12];
        #pragma unroll
        for (int r = 0; r < 12; ++r) bits[r] = (float)((sm[r * 64 + row] >> mb) & 1ull);
        #pragma unroll
        for (int s = 0; s < 2; ++s)
            #pragma unroll
            for (int q = 0; q < 6; ++q) {
                float v = 0.f;
                #pragma unroll
                for (int r = 0; r < 12; ++r) v += bits[r] * cmb[s][r][q];
                aq[(size_t)s * AQ_SETSTRIDE + ((size_t)b * 6 + q) * 4096 + pos] = f2bf(v);
            }
    }
}

// ---------------------------------------------------------------------------
// initial embedding -> mi1 rows 60..63 ; mi2 rows 62,63  (unchanged, validated)
__global__ void k_prep(const int* __restrict__ player,
                       const float* __restrict__ pAx, const float* __restrict__ pAy,
                       const float* __restrict__ pBx, const float* __restrict__ pBy,
                       const float* __restrict__ emb, const float* __restrict__ cW,
                       const float* __restrict__ cb, const float* __restrict__ inW,
                       const float* __restrict__ inb,
                       u16* __restrict__ mi1, u16* __restrict__ mi2) {
    int b = blockIdx.x, t = threadIdx.x;
    __shared__ float feat[2][64];
    if (t < 64) {
        int j = t >> 5, d = t & 31;
        float X = j ? pBx[b] : pAx[b];
        float Y = j ? pBy[b] : pAy[b];
        feat[j][d] = fmaxf(cW[d * 2] * X + cW[d * 2 + 1] * Y + cb[d], 0.f);
        feat[j][32 + d] = emb[player[b * 2 + j] * 32 + d];
    }
    __syncthreads();
    for (int h = t; h < 512; h += 256) {
        float a0 = inb[h], a1 = inb[h];
        const float* wrow = inW + h * 64;
        #pragma unroll
        for (int d = 0; d < 64; ++d) {
            float wv = wrow[d];
            a0 += wv * feat[0][d];
            a1 += wv * feat[1][d];
        }
        u16 v0 = f2bf(a0), v1 = f2bf(a1);
        size_t base = (size_t)b * 64 * 512;
        mi1[base + 60 * 512 + h] = v0;
        mi1[base + 61 * 512 + h] = v1;
        mi1[base + 62 * 512 + h] = 0;
        mi1[base + 63 * 512 + h] = 0;
        mi2[base + 62 * 512 + h] = v1;
        mi2[base + 63 * 512 + h] = 0;
    }
}

// enc f32 -> mi1 rows 0..59 ; mi2 rows 0..57  (unchanged, validated)
__global__ void k_cast(const float* __restrict__ enc, u16* __restrict__ mi1, u16* __restrict__ mi2) {
    long long e = ((long long)blockIdx.x * 256 + threadIdx.x) * 8;
    if (e >= 256LL * 60 * 512) return;
    int b = (int)(e / (60 * 512));
    int rm = (int)(e % (60 * 512));
    int n = rm / 512, h = rm % 512;
    for (int i = 0; i < 8; ++i) {
        u16 v = f2bf(enc[e + i]);
        mi1[((size_t)b * 64 + n) * 512 + h + i] = v;
        if (n < 58) mi2[((size_t)b * 64 + n) * 512 + h + i] = v;
    }
}

// ---------------------------------------------------------------------------
// Full RGCN layer via basis decomposition:
//   Y = relu( sum_q (A_q @ X) @ B_q  +  X @ selfW^T )
// v10: block = (batch, col-half). Grid 512 fills all 256 CUs (was 128).
// Each block computes the full T_q (8 waves x 64-h band, duplicated across
// the two halves) but only its 256-col output band (wave: 32 cols).
__global__ __launch_bounds__(512, 2)
void k_layer(const u16* __restrict__ x, const u16* __restrict__ aq,
             const u16* __restrict__ wc, u16* __restrict__ out) {
    int b = blockIdx.x >> 1, nh = blockIdx.x & 1;
    int t = threadIdx.x, lane = t & 63, w = t >> 6;
    int l15 = lane & 15, lq = lane >> 4;
    const int TS = 520;                      // T row stride (u16), pad vs 512
    __shared__ __align__(16) u16 T[64 * 520];

    const u16* xb_base = x + (size_t)b * 64 * 512;
    // X as B-operand frags (q-invariant): B[k=j, col=h], h-band = w*64
    short8 xb[8];
    #pragma unroll
    for (int nt = 0; nt < 4; ++nt)
        #pragma unroll
        for (int kh = 0; kh < 2; ++kh) {
            int h = (w * 4 + nt) * 16 + l15;
            int j0 = kh * 32 + lq * 8;
            short8 v;
            #pragma unroll
            for (int jj = 0; jj < 8; ++jj)
                v[jj] = (short)xb_base[(size_t)(j0 + jj) * 512 + h];
            xb[nt * 2 + kh] = v;
        }

    floatx4 acc[8];                          // [i 0..3][nt 0..1]
    #pragma unroll
    for (int i = 0; i < 8; ++i) acc[i] = (floatx4)(0.f);

    const u16* aqb   = aq + (size_t)b * 6 * 4096 + (size_t)lane * 8;
    const u16* wbase = wc + (size_t)lane * 8;
    int cf0 = nh * 16 + w * 2;               // wcat col-fragment base

    for (int q = 0; q < 6; ++q) {
        __syncthreads();   // previous q's T reads complete
        // ---- stage A: T_q[m][h-band w]  (full T, duplicated per col-half)
        for (int i = 0; i < 4; ++i) {
            short8 a0 = *(const short8*)(aqb + (size_t)q * 4096 + (i * 2 + 0) * 512);
            short8 a1 = *(const short8*)(aqb + (size_t)q * 4096 + (i * 2 + 1) * 512);
            #pragma unroll
            for (int nt = 0; nt < 4; ++nt) {
                floatx4 tz = (floatx4)(0.f);
                tz = __builtin_amdgcn_mfma_f32_16x16x32_bf16(a0, xb[nt * 2 + 0], tz, 0, 0, 0);
                tz = __builtin_amdgcn_mfma_f32_16x16x32_bf16(a1, xb[nt * 2 + 1], tz, 0, 0, 0);
                int hcol = (w * 4 + nt) * 16 + l15;
                int mrow = i * 16 + lq * 4;
                #pragma unroll
                for (int reg = 0; reg < 4; ++reg)
                    T[(mrow + reg) * TS + hcol] = f2bf(tz[reg]);
            }
        }
        __syncthreads();   // T_q visible
        // ---- stage B: acc += T_q @ B_q  (own 32-col band)
        for (int ks = 0; ks < 16; ++ks) {
            short8 af[4], bf[2];
            #pragma unroll
            for (int i = 0; i < 4; ++i)
                af[i] = *(const short8*)&T[(i * 16 + l15) * TS + ks * 32 + lq * 8];
            #pragma unroll
            for (int nt = 0; nt < 2; ++nt)
                bf[nt] = *(const short8*)(wbase + (size_t)(q * 16 + ks) * 16384 + (size_t)(cf0 + nt) * 512);
            #pragma unroll
            for (int i = 0; i < 4; ++i)
                #pragma unroll
                for (int nt = 0; nt < 2; ++nt)
                    acc[i * 2 + nt] = __builtin_amdgcn_mfma_f32_16x16x32_bf16(af[i], bf[nt], acc[i * 2 + nt], 0, 0, 0);
        }
    }
    // ---- slab 6: self term, A = X rows (row-major, contiguous)
    for (int ks = 0; ks < 16; ++ks) {
        short8 af[4], bf[2];
        #pragma unroll
        for (int i = 0; i < 4; ++i)
            af[i] = *(const short8*)(xb_base + (size_t)(i * 16 + l15) * 512 + ks * 32 + lq * 8);
        #pragma unroll
        for (int nt = 0; nt < 2; ++nt)
            bf[nt] = *(const short8*)(wbase + (size_t)(96 + ks) * 16384 + (size_t)(cf0 + nt) * 512);
        #pragma unroll
        for (int i = 0; i < 4; ++i)
            #pragma unroll
            for (int nt = 0; nt < 2; ++nt)
                acc[i * 2 + nt] = __builtin_amdgcn_mfma_f32_16x16x32_bf16(af[i], bf[nt], acc[i * 2 + nt], 0, 0, 0);
    }
    // ---- epilogue: relu, y[m = i*16+lq*4+reg][n = nh*256 + w*32 + nt*16 + l15]
    #pragma unroll
    for (int i = 0; i < 4; ++i)
        #pragma unroll
        for (int nt = 0; nt < 2; ++nt) {
            int n = nh * 256 + w * 32 + nt * 16 + l15;
            int m0 = i * 16 + lq * 4;
            #pragma unroll
            for (int reg = 0; reg < 4; ++reg)
                out[((size_t)b * 64 + m0 + reg) * 512 + n] = f2bf(fmaxf(acc[i * 2 + nt][reg], 0.f));
        }
}

// ---------------------------------------------------------------------------
// Final RGCN layer: only output rows 48..63 needed. v10 col-half split.
__global__ __launch_bounds__(512, 2)
void k_layer_last(const u16* __restrict__ x, const u16* __restrict__ aq,
                  const u16* __restrict__ wc, int mode,
                  u16* __restrict__ o16, float* __restrict__ o32) {
    int b = blockIdx.x >> 1, nh = blockIdx.x & 1;
    int t = threadIdx.x, lane = t & 63, w = t >> 6;
    int l15 = lane & 15, lq = lane >> 4;
    const int TS = 520;
    __shared__ __align__(16) u16 T[16 * 520];

    const u16* xb_base = x + (size_t)b * 64 * 512;
    short8 xb[8];
    #pragma unroll
    for (int nt = 0; nt < 4; ++nt)
        #pragma unroll
        for (int kh = 0; kh < 2; ++kh) {
            int h = (w * 4 + nt) * 16 + l15;
            int j0 = kh * 32 + lq * 8;
            short8 v;
            #pragma unroll
            for (int jj = 0; jj < 8; ++jj)
                v[jj] = (short)xb_base[(size_t)(j0 + jj) * 512 + h];
            xb[nt * 2 + kh] = v;
        }

    floatx4 acc[2];
    #pragma unroll
    for (int i = 0; i < 2; ++i) acc[i] = (floatx4)(0.f);

    const u16* aqb   = aq + (size_t)b * 6 * 4096 + (size_t)lane * 8;
    const u16* wbase = wc + (size_t)lane * 8;
    int cf0 = nh * 16 + w * 2;

    for (int q = 0; q < 6; ++q) {
        __syncthreads();
        // stage A: rows 48..63 only (frag i=3: f = 6,7)
        {
            short8 a0 = *(const short8*)(aqb + (size_t)q * 4096 + 6 * 512);
            short8 a1 = *(const short8*)(aqb + (size_t)q * 4096 + 7 * 512);
            #pragma unroll
            for (int nt = 0; nt < 4; ++nt) {
                floatx4 tz = (floatx4)(0.f);
                tz = __builtin_amdgcn_mfma_f32_16x16x32_bf16(a0, xb[nt * 2 + 0], tz, 0, 0, 0);
                tz = __builtin_amdgcn_mfma_f32_16x16x32_bf16(a1, xb[nt * 2 + 1], tz, 0, 0, 0);
                int hcol = (w * 4 + nt) * 16 + l15;
                int mrow = lq * 4;
                #pragma unroll
                for (int reg = 0; reg < 4; ++reg)
                    T[(mrow + reg) * TS + hcol] = f2bf(tz[reg]);
            }
        }
        __syncthreads();
        // stage B (own 32-col band)
        for (int ks = 0; ks < 16; ++ks) {
            short8 af = *(const short8*)&T[l15 * TS + ks * 32 + lq * 8];
            #pragma unroll
            for (int nt = 0; nt < 2; ++nt) {
                short8 bf = *(const short8*)(wbase + (size_t)(q * 16 + ks) * 16384 + (size_t)(cf0 + nt) * 512);
                acc[nt] = __builtin_amdgcn_mfma_f32_16x16x32_bf16(af, bf, acc[nt], 0, 0, 0);
            }
        }
    }
    // slab 6: self, X rows 48..63
    for (int ks = 0; ks < 16; ++ks) {
        short8 af = *(const short8*)(xb_base + (size_t)(48 + l15) * 512 + ks * 32 + lq * 8);
        #pragma unroll
        for (int nt = 0; nt < 2; ++nt) {
            short8 bf = *(const short8*)(wbase + (size_t)(96 + ks) * 16384 + (size_t)(cf0 + nt) * 512);
            acc[nt] = __builtin_amdgcn_mfma_f32_16x16x32_bf16(af, bf, acc[nt], 0, 0, 0);
        }
    }
    // epilogue: m = 48 + lq*4 + reg, n = nh*256 + w*32 + nt*16 + l15
    #pragma unroll
    for (int nt = 0; nt < 2; ++nt) {
        int n = nh * 256 + w * 32 + nt * 16 + l15;
        #pragma unroll
        for (int reg = 0; reg < 4; ++reg) {
            int m = 48 + lq * 4 + reg;
            float v = acc[nt][reg];
            if (mode == 1) {
                if (m >= 58 && m <= 61)
                    o16[((size_t)b * 64 + m) * 512 + n] = f2bf(1.f / (1.f + __expf(-v)));
            } else {
                if (m == 60 || m == 62) {
                    int slot = (m == 60) ? (b * 2) : (b * 2 + 1);
                    o32[(size_t)slot * 512 + n] = 1.f / (1.f + __expf(-v));
                }
            }
        }
    }
}

// logits = [black|white] @ type_W^T + type_b  (unchanged, validated)
__global__ void k_final(const float* __restrict__ t2, const float* __restrict__ tW,
                        const float* __restrict__ tb, float* __restrict__ outp) {
    int b = blockIdx.x, l = threadIdx.x;   // 64 threads
    float a[11];
    #pragma unroll
    for (int j = 0; j < 11; ++j) a[j] = 0.f;
    for (int it = 0; it < 16; ++it) {
        int h = it * 64 + l;
        float c = (h < 512) ? t2[(b * 2 + 1) * 512 + h] : t2[(b * 2 + 0) * 512 + (h - 512)];
        #pragma unroll
        for (int j = 0; j < 11; ++j) a[j] += c * tW[j * 1024 + h];
    }
    #pragma unroll
    for (int j = 0; j < 11; ++j) {
        float v = a[j];
        for (int off = 32; off > 0; off >>= 1) v += __shfl_down(v, off, 64);
        if (l == 0) outp[b * 11 + j] = v + tb[j];
    }
}

// ---------------------------------------------------------------------------
extern "C" void kernel_launch(void* const* d_in, const int* in_sizes, int n_in,
                              void* d_out, int out_size, void* d_ws, size_t ws_size,
                              hipStream_t stream) {
    const int*   player = (const int*)d_in[0];
    const float* enc    = (const float*)d_in[2];
    const int*   adjm   = (const int*)d_in[3];
    const float* pAx    = (const float*)d_in[4];
    const float* pAy    = (const float*)d_in[5];
    const float* pBx    = (const float*)d_in[6];
    const float* pBy    = (const float*)d_in[7];
    const float* emb    = (const float*)d_in[8];
    const float* cW     = (const float*)d_in[9];
    const float* cb     = (const float*)d_in[10];
    const float* inW    = (const float*)d_in[11];
    const float* inb    = (const float*)d_in[12];
    const float* basis0 = (const float*)d_in[13];
    const float* comb0  = (const float*)d_in[14];
    const float* self0  = (const float*)d_in[15];
    const float* basis1 = (const float*)d_in[16];
    const float* comb1  = (const float*)d_in[17];
    const float* self1  = (const float*)d_in[18];
    const float* typeW  = (const float*)d_in[19];
    const float* typeb  = (const float*)d_in[20];

    char* ws = (char*)d_ws;
    size_t off = 0;
    auto alloc = [&](size_t bytes) -> void* {
        void* p = ws + off;
        off = (off + bytes + 255) & ~(size_t)255;
        return p;
    };
    // Workspace (peak ~86.5 MB, under proven 89 MB):
    //   mi1 region: mi1 (prep..layer1) -> x12b (layer3..layer4)
    //   x12 region: x12 (layer1..layer2) -> t2 (layer4..final)
    //   aq region: [set0|set1] variant0 (..layer2) -> variant1 (..layer4)
    u16* mi1   = (u16*)alloc(256UL * 64 * 512 * 2);
    u16* mi2   = (u16*)alloc(256UL * 64 * 512 * 2);
    u16* x12   = (u16*)alloc(256UL * 64 * 512 * 2);
    u16* aqbuf = (u16*)alloc(2UL * AQ_SETSTRIDE * 2);
    u16* wcat0 = (u16*)alloc(3584UL * 512 * 2);
    u16* wcat1 = (u16*)alloc(3584UL * 512 * 2);
    u64* mm0   = (u64*)alloc(256UL * 12 * 64 * 8);
    u64* mm1   = (u64*)alloc(256UL * 12 * 64 * 8);
    u16* x12b  = mi1;             // mi1 dead after layer 1
    float* t2  = (float*)x12;     // x12 dead after layer 2
    u16* aq0   = aqbuf;
    u16* aq1   = aqbuf + AQ_SETSTRIDE;

    k_wcat<<<448, 256, 0, stream>>>(basis0, self0, wcat0);
    k_wcat<<<448, 256, 0, stream>>>(basis1, self1, wcat1);
    k_masks<<<3072, 64, 0, stream>>>(adjm, mm0, mm1);
    k_aqexp<<<2048, 256, 0, stream>>>(mm0, comb0, comb1, aqbuf);
    k_prep<<<256, 256, 0, stream>>>(player, pAx, pAy, pBx, pBy, emb, cW, cb, inW, inb, mi1, mi2);
    k_cast<<<3840, 256, 0, stream>>>(enc, mi1, mi2);

    // rgcn pass 1
    k_layer<<<512, 512, 0, stream>>>(mi1, aq0, wcat0, x12);
    k_layer_last<<<512, 512, 0, stream>>>(x12, aq1, wcat1, 1, mi2, nullptr);
    // regenerate weighted adjacency for the pruned pass-2 graph
    k_aqexp<<<2048, 256, 0, stream>>>(mm1, comb0, comb1, aqbuf);
    // rgcn pass 2
    k_layer<<<512, 512, 0, stream>>>(mi2, aq0, wcat0, x12b);
    k_layer_last<<<512, 512, 0, stream>>>(x12b, aq1, wcat1, 2, nullptr, t2);

    k_final<<<256, 64, 0, stream>>>(t2, typeW, typeb, (float*)d_out);
}